// Round 7
// baseline (735.852 us; speedup 1.0000x reference)
//
#include <hip/hip_runtime.h>
#include <hip/hip_bf16.h>
#include <hip/hip_fp16.h>

// MetaGIN round 11:
//  - k_agg: src payload unified into pk3 = [h0,ug0,uv0] per channel-pair
//    (one address chain, 3 dword loads at imm offsets); 2-deep payload
//    software pipeline (A/B rotate, descriptors 3 ahead).
//  - k_pre: mats 0,1,2 write pk3 slots 0,1,2; mat 3 (h1) writes d_out.
//  - chain unchanged: memset ; k_init_hist ; k_pre_scan1 ; k_scan3 ;
//    k_scatter ; k_agg ; k_post.
//
// ws layout: aggh N*128 f16 | pk3 N*192 u32 | pb16 arena | gembh 33*128 f16 |
//            gsums 256 f32 | cnt N | off N | bsum 1024 | sedge E uint2 (~215MB)
// h1 (N*64 u32 f16-pairs) lives in d_out (overwritten by k_post at the end).

typedef unsigned short u16;
typedef unsigned int   u32;

#define WIDTH 128

// params arena element offsets (bf16 except GW/VW/PW/WGC/WVC/BGC/BVC = f16)
#define OFF_W0   0        // 16384
#define OFF_B0   16384    // 128
#define OFF_W1   16512    // 16384
#define OFF_B1   32896    // 128
#define OFF_EMB  33024    // 33*128 = 4224
#define OFF_GW   37248    // 128*16 = 2048 (f16)
#define OFF_VW   39296    // 2048 (f16)
#define OFF_PW   41344    // 16384 (f16)
#define OFF_PB   57728    // 128
#define OFF_DP   57856    // 128
#define OFF_WGC  57984    // 16384 (f16)  composite G.W0
#define OFF_WVC  74368    // 16384 (f16)  composite V.W0
#define OFF_BGC  90752    // 128 (f16)    composite G.b0
#define OFF_BVC  90880    // 128 (f16)    composite V.b0
#define OFF_DEG  91008    // N (bf16)
#define ARENA_PAD 291072  // u16 elems (>= OFF_DEG+N, even)

typedef __attribute__((ext_vector_type(8))) short bf16x8;
typedef __attribute__((ext_vector_type(8))) _Float16 f16x8;
typedef __attribute__((ext_vector_type(4))) float f32x4;
typedef __attribute__((ext_vector_type(2))) __fp16 f16x2;

__device__ __forceinline__ float b2f(u16 u){ return __uint_as_float(((u32)u) << 16); }
__device__ __forceinline__ u16   f2b(float f){
  u32 u = __float_as_uint(f);
  u += 0x7fffu + ((u >> 16) & 1u);   // RNE
  return (u16)(u >> 16);
}
__device__ __forceinline__ u16   f2h(float f){ return __half_as_ushort(__float2half(f)); }
__device__ __forceinline__ float h2f(u16 u){ return __half2float(__ushort_as_half(u)); }

__device__ __forceinline__ f16x2 u2h(u32 u){ union { u32 a; f16x2 b; } c; c.a = u; return c.b; }
__device__ __forceinline__ u32   h2u(f16x2 h){ union { f16x2 b; u32 a; } c; c.b = h; return c.a; }

__device__ __forceinline__ f16x2 pkhfma(f16x2 a, f16x2 b, f16x2 c){
#if __has_builtin(__builtin_elementwise_fma)
  return __builtin_elementwise_fma(a, b, c);
#else
  return a * b + c;
#endif
}

// s += dpp_xlane(s); 0xB1=quad_perm xor1, 0x4E=quad_perm xor2,
// 0x141=row_half_mirror (xor7 within 8) -> full 8-lane butterfly in VALU.
#define DPPADD(s, ctrl) {                                                  \
  const float _t = __uint_as_float((u32)__builtin_amdgcn_update_dpp(       \
      0, (int)__float_as_uint(s), (ctrl), 0xF, 0xF, true));                \
  (s) += _t; }

__device__ __forceinline__ bool is_fp32(const void* degsrc){
  // deg = exact ints 1..7: fp32 word0 low16 == 0; bf16 word0 low16 != 0
  return ((*(const u32*)degsrc) & 0xffffu) == 0u;
}

__device__ __forceinline__ bf16x8 cvt8(float4 a, float4 b){
  bf16x8 r;
  r[0]=(short)f2b(a.x); r[1]=(short)f2b(a.y); r[2]=(short)f2b(a.z); r[3]=(short)f2b(a.w);
  r[4]=(short)f2b(b.x); r[5]=(short)f2b(b.y); r[6]=(short)f2b(b.z); r[7]=(short)f2b(b.w);
  return r;
}
__device__ __forceinline__ f16x8 cvt8h(float4 a, float4 b){
  f16x8 r;
  r[0]=(_Float16)a.x; r[1]=(_Float16)a.y; r[2]=(_Float16)a.z; r[3]=(_Float16)a.w;
  r[4]=(_Float16)b.x; r[5]=(_Float16)b.y; r[6]=(_Float16)b.z; r[7]=(_Float16)b.w;
  return r;
}
__device__ __forceinline__ f16x8 cvtbh(bf16x8 v){
  f16x8 r;
  #pragma unroll
  for (int j = 0; j < 8; ++j) r[j] = (_Float16)b2f((u16)v[j]);
  return r;
}

__device__ __forceinline__ u16 cvt_one(const void* src, int j, bool f32){
  return f32 ? f2b(((const float*)src)[j]) : ((const u16*)src)[j];
}
__device__ __forceinline__ u16 cvt_one_h(const void* src, int j, bool f32){
  return f32 ? f2h(((const float*)src)[j]) : f2h(b2f(((const u16*)src)[j]));
}
__device__ __forceinline__ float read_f(const void* src, int j, bool f32){
  return f32 ? ((const float*)src)[j] : b2f(((const u16*)src)[j]);
}

// ---------------------------------------------------------------------------
// k_init_hist: {degree histogram | convert params+deg | gemb(f16) | gsums |
// composite W0 weights/biases}. cnt pre-zeroed via hipMemsetAsync.
// ---------------------------------------------------------------------------
__global__ void k_init_hist(const void* w0, const void* b0, const void* w1, const void* b1,
                            const void* emb, const void* gw, const void* vw,
                            const void* pw, const void* pb, const void* dp,
                            const void* degsrc, const int* __restrict__ eidx,
                            int* __restrict__ cnt, int E,
                            u16* __restrict__ pb16, u16* __restrict__ gembh,
                            float* __restrict__ gsums, int N)
{
  const bool f32 = is_fp32(degsrc);
  const int nbh = (E + 255) >> 8;
  const int tot_cvt = OFF_WGC + N;
  const int nbc = (tot_cvt + 255) >> 8;
  int b = blockIdx.x;
  const int t = threadIdx.x;

  if (b < nbh) {                       // degree histogram
    const int e = b * 256 + t;
    if (e < E) atomicAdd(&cnt[eidx[E + e]], 1);
    return;
  }
  b -= nbh;
  if (b < nbc) {                       // convert params (+deg)
    const int i = b * 256 + t;
    if (i >= tot_cvt) return;
    u16 v; int dsti = i;
    if      (i < OFF_B0 ) v = cvt_one(w0,  i,           f32);
    else if (i < OFF_W1 ) v = cvt_one(b0,  i - OFF_B0,  f32);
    else if (i < OFF_B1 ) v = cvt_one(w1,  i - OFF_W1,  f32);
    else if (i < OFF_EMB) v = cvt_one(b1,  i - OFF_B1,  f32);
    else if (i < OFF_GW ) v = cvt_one(emb, i - OFF_EMB, f32);
    else if (i < OFF_VW ) v = cvt_one_h(gw, i - OFF_GW, f32);   // f16
    else if (i < OFF_PW ) v = cvt_one_h(vw, i - OFF_VW, f32);   // f16
    else if (i < OFF_PB ) v = cvt_one_h(pw, i - OFF_PW, f32);   // f16
    else if (i < OFF_DP ) v = cvt_one(pb,  i - OFF_PB,  f32);
    else if (i < OFF_WGC) v = cvt_one(dp,  i - OFF_DP,  f32);
    else { v = cvt_one(degsrc, i - OFF_WGC, f32); dsti = OFF_DEG + (i - OFF_WGC); }
    pb16[dsti] = v;
    return;
  }
  b -= nbc;
  if (b < 17) {                        // gemb (f16): gemb[a][c] = G[c].emb[a]
    const int tid = b * 256 + t;
    if (tid >= 33 * 128) return;
    const int a = tid >> 7, c = tid & 127, g = c >> 4;
    float s = 0.f;
    #pragma unroll
    for (int i = 0; i < 16; ++i)
      s += read_f(gw, c * 16 + i, f32) * read_f(emb, a * WIDTH + g * 16 + i, f32);
    gembh[tid] = f2h(s);
    return;
  }
  b -= 17;
  if (b < 1) {                         // gsums: [0,128)=rowsum(gw), [128,256)=rowsum(vw)
    if (t < 256) {
      const int c = t & 127;
      const void* src = (t >> 7) ? vw : gw;
      float s = 0.f;
      #pragma unroll
      for (int i = 0; i < 16; ++i) s += read_f(src, c * 16 + i, f32);
      gsums[t] = s;
    }
    return;
  }
  b -= 1;
  if (b < 128) {                       // composite weights: (G|V).W0 -> f16
    const int tid = b * 256 + t;      // 0..32767
    const int m = tid >> 14;          // 0: gate, 1: value
    const int o = (tid >> 7) & 127;
    const int i = tid & 127;
    const void* wsel = m ? vw : gw;
    const int hb = (o >> 4) * 16;
    float s = 0.f;
    #pragma unroll
    for (int j = 0; j < 16; ++j)
      s += read_f(wsel, o * 16 + j, f32) * read_f(w0, (size_t)(hb + j) * 128 + i, f32);
    pb16[(m ? OFF_WVC : OFF_WGC) + o * 128 + i] = f2h(s);
    return;
  }
  // composite biases: (G|V).b0 -> f16
  if (t < 256) {
    const int m = t >> 7, o = t & 127, hb = (o >> 4) * 16;
    const void* wsel = m ? vw : gw;
    float s = 0.f;
    #pragma unroll
    for (int j = 0; j < 16; ++j)
      s += read_f(wsel, o * 16 + j, f32) * read_f(b0, hb + j, f32);
    pb16[(m ? OFF_BVC : OFF_BGC) + o] = f2h(s);
  }
}

// ---------------------------------------------------------------------------
// k_pre_scan1: 512 threads. Blocks [0,npre): 8 warps = 4 mats x 2 ch-halves
// over a 64-node tile. mats: 0=h0(W0,bf16)->pk3 slot0, 1=ug0(G.W0,f16)->
// pk3 slot1, 2=uv0(V.W0,f16)->pk3 slot2, 3=h1(W1,bf16)->d_out.
// Even/odd fragment pair-trick -> lane owns adjacent channel pair.
// Blocks [npre,..): scan1 block sums (needs hist done).
// ---------------------------------------------------------------------------
__global__ __launch_bounds__(512, 2) void k_pre_scan1(
    const void* __restrict__ x, const u16* __restrict__ pb16,
    u32* __restrict__ pk3, u32* __restrict__ h1d,
    const void* __restrict__ degsrc,
    const int* __restrict__ cnt, int* __restrict__ bsum, int n, int npre)
{
  if ((int)blockIdx.x >= npre) {       // scan1: 1024 elems, 2 per thread
    const int t = threadIdx.x, b = (int)blockIdx.x - npre;
    const int i0 = b * 1024 + t * 2;
    int s = 0;
    if (i0     < n) s += cnt[i0];
    if (i0 + 1 < n) s += cnt[i0 + 1];
    __shared__ int sb[512];
    sb[t] = s; __syncthreads();
    for (int d = 256; d > 0; d >>= 1) { if (t < d) sb[t] += sb[t + d]; __syncthreads(); }
    if (t == 0) bsum[b] = sb[0];
    return;
  }

  const int t = threadIdx.x;
  const int lane = t & 63, lid = lane & 15, quad = lane >> 4;
  const int w = t >> 6, mat = w >> 1, c0 = (w & 1) * 64;
  const int node0 = blockIdx.x * 64;
  const bool f32 = is_fp32(degsrc);
  const bool hp16 = (mat == 1) || (mat == 2);   // f16 composite path

  const u16* wsrc; const u16* bsv;
  u32* outp;
  if      (mat == 0) { wsrc = pb16 + OFF_W0;  bsv = pb16 + OFF_B0;  outp = pk3; }
  else if (mat == 1) { wsrc = pb16 + OFF_WGC; bsv = pb16 + OFF_BGC; outp = pk3; }
  else if (mat == 2) { wsrc = pb16 + OFF_WVC; bsv = pb16 + OFF_BVC; outp = pk3; }
  else               { wsrc = pb16 + OFF_W1;  bsv = pb16 + OFF_B1;  outp = h1d; }

  float bias[2][2];
  #pragma unroll
  for (int ntp = 0; ntp < 2; ++ntp)
    #pragma unroll
    for (int eo = 0; eo < 2; ++eo) {
      const u16 braw = bsv[c0 + ntp * 32 + 2 * lid + eo];
      bias[ntp][eo] = hp16 ? h2f(braw) : b2f(braw);
    }

  f32x4 acc[4][2][2];
  #pragma unroll
  for (int mt = 0; mt < 4; ++mt)
    #pragma unroll
    for (int ntp = 0; ntp < 2; ++ntp)
      #pragma unroll
      for (int eo = 0; eo < 2; ++eo)
        #pragma unroll
        for (int r = 0; r < 4; ++r) acc[mt][ntp][eo][r] = bias[ntp][eo];

  if (!hp16) {         // bf16 path
    #pragma unroll
    for (int ks = 0; ks < 4; ++ks) {
      bf16x8 a[4], bb[2][2];
      #pragma unroll
      for (int ntp = 0; ntp < 2; ++ntp)
        #pragma unroll
        for (int eo = 0; eo < 2; ++eo)
          bb[ntp][eo] = *(const bf16x8*)(wsrc +
              (size_t)(c0 + ntp * 32 + 2 * lid + eo) * WIDTH + ks * 32 + quad * 8);
      if (f32) {
        #pragma unroll
        for (int mt = 0; mt < 4; ++mt) {
          const float4* xr = (const float4*)((const float*)x +
              (size_t)(node0 + mt * 16 + lid) * WIDTH + ks * 32 + quad * 8);
          a[mt] = cvt8(xr[0], xr[1]);
        }
      } else {
        #pragma unroll
        for (int mt = 0; mt < 4; ++mt)
          a[mt] = *(const bf16x8*)((const u16*)x +
              (size_t)(node0 + mt * 16 + lid) * WIDTH + ks * 32 + quad * 8);
      }
      #pragma unroll
      for (int mt = 0; mt < 4; ++mt)
        #pragma unroll
        for (int ntp = 0; ntp < 2; ++ntp)
          #pragma unroll
          for (int eo = 0; eo < 2; ++eo)
            acc[mt][ntp][eo] = __builtin_amdgcn_mfma_f32_16x16x32_bf16(
                a[mt], bb[ntp][eo], acc[mt][ntp][eo], 0, 0, 0);
    }
  } else {             // f16 composite path
    #pragma unroll
    for (int ks = 0; ks < 4; ++ks) {
      f16x8 a[4], bb[2][2];
      #pragma unroll
      for (int ntp = 0; ntp < 2; ++ntp)
        #pragma unroll
        for (int eo = 0; eo < 2; ++eo)
          bb[ntp][eo] = *(const f16x8*)(wsrc +
              (size_t)(c0 + ntp * 32 + 2 * lid + eo) * WIDTH + ks * 32 + quad * 8);
      if (f32) {
        #pragma unroll
        for (int mt = 0; mt < 4; ++mt) {
          const float4* xr = (const float4*)((const float*)x +
              (size_t)(node0 + mt * 16 + lid) * WIDTH + ks * 32 + quad * 8);
          a[mt] = cvt8h(xr[0], xr[1]);
        }
      } else {
        #pragma unroll
        for (int mt = 0; mt < 4; ++mt)
          a[mt] = cvtbh(*(const bf16x8*)((const u16*)x +
              (size_t)(node0 + mt * 16 + lid) * WIDTH + ks * 32 + quad * 8));
      }
      #pragma unroll
      for (int mt = 0; mt < 4; ++mt)
        #pragma unroll
        for (int ntp = 0; ntp < 2; ++ntp)
          #pragma unroll
          for (int eo = 0; eo < 2; ++eo)
            acc[mt][ntp][eo] = __builtin_amdgcn_mfma_f32_16x16x32_f16(
                a[mt], bb[ntp][eo], acc[mt][ntp][eo], 0, 0, 0);
    }
  }

  // epilogue: adjacent-pair pack, dword stores
  #pragma unroll
  for (int mt = 0; mt < 4; ++mt)
    #pragma unroll
    for (int r = 0; r < 4; ++r) {
      const int node = node0 + mt * 16 + quad * 4 + r;
      #pragma unroll
      for (int ntp = 0; ntp < 2; ++ntp) {
        const int p = (c0 >> 1) + ntp * 16 + lid;
        const u32 pk = h2u(__builtin_amdgcn_cvt_pkrtz(
            acc[mt][ntp][0][r], acc[mt][ntp][1][r]));
        if (mat < 3) outp[(size_t)node * 192 + p * 3 + mat];
        if (mat < 3) outp[(size_t)node * 192 + p * 3 + mat] = pk;
        else         outp[(size_t)node * 64 + p] = pk;
      }
    }
}

// ---------------------------------------------------------------------------
// k_scan3: full exclusive scan (folds scan2's bsum prefix in per block).
// ---------------------------------------------------------------------------
__global__ void k_scan3(const int* __restrict__ cnt, const int* __restrict__ bsum,
                        int* __restrict__ off, int n){
  const int t = threadIdx.x, b = blockIdx.x;
  __shared__ int sp[256];
  int pv = 0;
  for (int j = t; j < b; j += 256) pv += bsum[j];
  sp[t] = pv; __syncthreads();
  for (int d = 128; d > 0; d >>= 1) { if (t < d) sp[t] += sp[t + d]; __syncthreads(); }
  const int bpref = sp[0];

  const int i0 = b * 1024 + t * 4;
  int c[4];
  #pragma unroll
  for (int j = 0; j < 4; ++j) { int i = i0 + j; c[j] = (i < n) ? cnt[i] : 0; }
  int tsum = c[0] + c[1] + c[2] + c[3];
  __shared__ int sb[256];
  sb[t] = tsum; __syncthreads();
  for (int d = 1; d < 256; d <<= 1) {
    int x = (t >= d) ? sb[t - d] : 0;
    __syncthreads();
    sb[t] += x;
    __syncthreads();
  }
  int run = bpref + sb[t] - tsum;
  #pragma unroll
  for (int j = 0; j < 4; ++j) {
    int i = i0 + j;
    if (i < n) off[i] = run;
    run += c[j];
  }
}

// scatter edges into dst-sorted order; one 8B store per edge; cb at bits 18-19.
// off[dst] becomes END pointer after this.
__global__ void k_scatter(const int* __restrict__ eidx, const int* __restrict__ eattr,
                          int* __restrict__ off, uint2* __restrict__ sedge, int E){
  const int e = blockIdx.x * 256 + threadIdx.x;
  if (e >= E) return;
  const int dst = eidx[E + e];
  const int pos = atomicAdd(&off[dst], 1);
  const u32 a0 = (u32)eattr[e*3+0], a1 = (u32)eattr[e*3+1], a2 = (u32)eattr[e*3+2];
  u32 cb = (a0 != 0) + (a1 != 0) + (a2 != 0);
  cb = cb ? cb : 1u;
  sedge[pos] = make_uint2((u32)eidx[e], a0 | (a1 << 6) | (a2 << 12) | (cb << 18));
}

// ---------------------------------------------------------------------------
// k_agg: one wave per 4 consecutive dst nodes. Lane q owns channels
// {2q,2q+1}; 8-lane clusters = one 16-ch head. gemb in LDS.
// Per dst:  DSTEP swizzle conv of h1 row (ug1/uv1), pk_fma_f16.
// Per edge: pk3 triple (1 addr chain, 3 dwords) + 3 ds_read gemb; DPP stats.
// 2-deep payload pipeline: payloads for i+1 (A<-B rotate) and i+2 in flight.
// ---------------------------------------------------------------------------
__global__ __launch_bounds__(256, 6) void k_agg(
    const u32* __restrict__ pk3, const u32* __restrict__ h1d,
    const uint2* __restrict__ sedge, const int* __restrict__ off,
    const u16* __restrict__ pb16, const u32* __restrict__ gembw,
    const float* __restrict__ gsums, u16* __restrict__ aggh, const int N)
{
  __shared__ u32 gl[2112];             // gemb f16[33][128] as u32 pairs
  for (int j = threadIdx.x; j < 2112; j += 256) gl[j] = gembw[j];
  __syncthreads();

  const int base = ((blockIdx.x * 256 + threadIdx.x) >> 6) * 4;
  if (base >= N) return;
  const int q = threadIdx.x & 63;
  const int c0 = 2 * q;           // my channels: c0, c0+1

  // packed f16 conv weight rows c0, c0+1 (for the per-dst h1 conv)
  u32 gw0[8], gw1[8], vw0[8], vw1[8];
  {
    const u32* g = (const u32*)(pb16 + OFF_GW + (size_t)c0 * 16);
    const u32* v = (const u32*)(pb16 + OFF_VW + (size_t)c0 * 16);
    #pragma unroll
    for (int i = 0; i < 8; ++i) {
      gw0[i] = g[i]; gw1[i] = g[8 + i];
      vw0[i] = v[i]; vw1[i] = v[8 + i];
    }
  }
  const float gs0 = gsums[c0],       gs1 = gsums[c0 + 1];
  const float vs0 = gsums[128 + c0], vs1 = gsums[128 + c0 + 1];

  u32 h1w[4]; int nend[4];
  #pragma unroll
  for (int d = 0; d < 4; ++d) {
    const int dst = min(base + d, N - 1);
    h1w[d]  = h1d[(size_t)dst * 64 + q];
    nend[d] = off[dst];
  }
  int ncur = base ? off[base - 1] : 0;
  const int nlast = nend[3];

  // 2-deep payload pipeline: A = edge i, B = edge i+1, edd = descriptor i+2
  u32 A_h = 0, A_g = 0, A_v = 0, A_g0 = 0, A_g1 = 0, A_g2 = 0; float A_inv = 1.f;
  u32 B_h = 0, B_g = 0, B_v = 0, B_g0 = 0, B_g1 = 0, B_g2 = 0; float B_inv = 1.f;
  uint2 edd = make_uint2(0u, 0u);

#define LOADP(P, DSC) {                                                        \
    const u32* pp = pk3 + (size_t)((DSC).x * 192u + (u32)(q * 3));             \
    P##_h = pp[0]; P##_g = pp[1]; P##_v = pp[2];                               \
    const int a0 = (DSC).y & 63, a1 = ((DSC).y >> 6) & 63, a2 = ((DSC).y >> 12) & 63; \
    P##_g0 = gl[a0 * 64 + q]; P##_g1 = gl[a1 * 64 + q]; P##_g2 = gl[a2 * 64 + q]; \
    P##_inv = __builtin_amdgcn_rcpf((float)(((DSC).y >> 18) & 3)); }

  if (ncur < nlast) {
    const uint2 d0 = sedge[ncur];
    const uint2 d1 = sedge[min(ncur + 1, nlast - 1)];
    edd = sedge[min(ncur + 2, nlast - 1)];
    LOADP(A, d0)
    LOADP(B, d1)
  }

  #pragma unroll
  for (int d = 0; d < 4; ++d) {
    const f16x2 h1h = u2h(h1w[d]);

    // per-dst grouped conv of h1 row: packed f16 pk_fma, literal weight index
    f16x2 ag0 = u2h(0), ag1 = u2h(0), av0 = u2h(0), av1 = u2h(0);
#define DSTEP(J) {                                                             \
    const f16x2 xj = u2h((u32)__builtin_amdgcn_ds_swizzle(                     \
        (int)h1w[d], 0x18 | ((J) << 5)));                                      \
    ag0 = pkhfma(xj, u2h(gw0[J]), ag0);                                        \
    ag1 = pkhfma(xj, u2h(gw1[J]), ag1);                                        \
    av0 = pkhfma(xj, u2h(vw0[J]), av0);                                        \
    av1 = pkhfma(xj, u2h(vw1[J]), av1); }
    DSTEP(0) DSTEP(1) DSTEP(2) DSTEP(3) DSTEP(4) DSTEP(5) DSTEP(6) DSTEP(7)
#undef DSTEP
    const float ug1d0 = (float)ag0.x + (float)ag0.y;
    const float ug1d1 = (float)ag1.x + (float)ag1.y;
    const float uv1d0 = (float)av0.x + (float)av0.y;
    const float uv1d1 = (float)av1.x + (float)av1.y;

    const int n1 = nend[d];
    float acc0 = 0.f, acc1 = 0.f;

    for (int i = ncur; i < n1; ++i) {
      // consume A (edge i)
      const u32 hp_c = A_h, ug_c = A_g, uv_c = A_v;
      const u32 g0c = A_g0, g1c = A_g1, g2c = A_g2;
      const float inv_c = A_inv;

      // rotate: A <- B; B <- load(edd); edd <- descriptor i+3
      A_h = B_h; A_g = B_g; A_v = B_v;
      A_g0 = B_g0; A_g1 = B_g1; A_g2 = B_g2; A_inv = B_inv;
      {
        const uint2 en = edd;
        edd = sedge[min(i + 3, nlast - 1)];
        LOADP(B, en)
      }

      // x = h0[src] + h1[dst], packed f16 (raw, un-normalized)
      const f16x2 xh = u2h(hp_c) + h1h;
      const float x0 = (float)xh.x, x1 = (float)xh.y;

      // stats over 16-ch head via DPP butterfly
      float s  = x0 + x1;
      float ss = fmaf(x0, x0, x1 * x1);
      DPPADD(s, 0xB1);  DPPADD(ss, 0xB1);
      DPPADD(s, 0x4E);  DPPADD(ss, 0x4E);
      DPPADD(s, 0x141); DPPADD(ss, 0x141);
      const float mean = s * 0.0625f;
      const float var  = fmaf(ss, 0.0625f, -mean * mean);
      const float rs   = __builtin_amdgcn_rsqf(var + 1e-5f);
      const float mrs  = mean * rs;

      // bag (pre-projected through gate weights), f16 sum then scale
      const f16x2 bsum3 = u2h(g0c) + u2h(g1c) + u2h(g2c);
      const float bg0 = (float)bsum3.x * inv_c;
      const float bg1 = (float)bsum3.y * inv_c;

      // gate = rs*(ug0+ug1) - mrs*gsum + bag ; val = rs*(uv0+uv1) - mrs*vsum
      const f16x2 ugh = u2h(ug_c), uvh = u2h(uv_c);
      const float gate0 = fmaf(rs, (float)ugh.x + ug1d0, fmaf(-mrs, gs0, bg0));
      const float gate1 = fmaf(rs, (float)ugh.y + ug1d1, fmaf(-mrs, gs1, bg1));
      const float val0  = fmaf(rs, (float)uvh.x + uv1d0, -mrs * vs0);
      const float val1  = fmaf(rs, (float)uvh.y + uv1d1, -mrs * vs1);
      acc0 = fmaf(fmaxf(gate0, 0.f), val0, acc0);
      acc1 = fmaf(fmaxf(gate1, 0.f), val1, acc1);
    }

    if (base + d < N)
      *(u32*)(aggh + (size_t)(base + d) * WIDTH + c0) =
          h2u(__builtin_amdgcn_cvt_pkrtz(acc0, acc1));
    ncur = n1;
  }
#undef LOADP
}

// ---------------------------------------------------------------------------
// k_post: out = (agg @ pw^T + pb) * deg^dp via f16 MFMA (agg & pw are f16).
// ---------------------------------------------------------------------------
__global__ __launch_bounds__(256, 2) void k_post(
    const u16* __restrict__ aggh, const u16* __restrict__ pb16,
    void* __restrict__ out, const void* __restrict__ degsrc)
{
  const int t = threadIdx.x;
  const int lane = t & 63, lid = lane & 15, quad = lane >> 4;
  const int w = t >> 6, c0 = (w & 1) * 64, mh = (w >> 1) * 32;
  const int node0 = blockIdx.x * 64;
  const bool f32o = is_fp32(degsrc);

  f32x4 acc[2][4];
  float dpc[4];
  #pragma unroll
  for (int nt = 0; nt < 4; ++nt) {
    const float bias = b2f(pb16[OFF_PB + c0 + nt * 16 + lid]);
    dpc[nt] = b2f(pb16[OFF_DP + c0 + nt * 16 + lid]);
    #pragma unroll
    for (int mt = 0; mt < 2; ++mt)
      #pragma unroll
      for (int r = 0; r < 4; ++r) acc[mt][nt][r] = bias;
  }

  #pragma unroll
  for (int ks = 0; ks < 4; ++ks) {
    f16x8 a[2], b[4];
    #pragma unroll
    for (int nt = 0; nt < 4; ++nt)
      b[nt] = *(const f16x8*)(pb16 + OFF_PW + (size_t)(c0 + nt * 16 + lid) * WIDTH + ks * 32 + quad * 8);
    #pragma unroll
    for (int mt = 0; mt < 2; ++mt)
      a[mt] = *(const f16x8*)(aggh +
          (size_t)(node0 + mh + mt * 16 + lid) * WIDTH + ks * 32 + quad * 8);
    #pragma unroll
    for (int mt = 0; mt < 2; ++mt)
      #pragma unroll
      for (int nt = 0; nt < 4; ++nt)
        acc[mt][nt] = __builtin_amdgcn_mfma_f32_16x16x32_f16(a[mt], b[nt], acc[mt][nt], 0, 0, 0);
  }

  float logd[2][4];
  #pragma unroll
  for (int mt = 0; mt < 2; ++mt)
    #pragma unroll
    for (int r = 0; r < 4; ++r)
      logd[mt][r] = __logf(b2f(pb16[OFF_DEG + node0 + mh + mt * 16 + quad * 4 + r]));

  #pragma unroll
  for (int mt = 0; mt < 2; ++mt)
    #pragma unroll
    for (int nt = 0; nt < 4; ++nt)
      #pragma unroll
      for (int r = 0; r < 4; ++r) {
        const int node = node0 + mh + mt * 16 + quad * 4 + r;
        const float v = acc[mt][nt][r] * __expf(dpc[nt] * logd[mt][r]);
        if (f32o) ((float*)out)[(size_t)node * WIDTH + c0 + nt * 16 + lid] = v;
        else      ((u16*)out)[(size_t)node * WIDTH + c0 + nt * 16 + lid] = f2b(v);
      }
}

extern "C" void kernel_launch(void* const* d_in, const int* in_sizes, int n_in,
                              void* d_out, int out_size, void* d_ws, size_t ws_size,
                              hipStream_t stream)
{
  (void)n_in; (void)out_size; (void)ws_size;
  const void* x     = d_in[0];
  const void* deg   = d_in[1];
  const int*  eidx  = (const int*)d_in[2];
  const int*  eattr = (const int*)d_in[3];

  const int N = in_sizes[1];            // 200000
  const int E = in_sizes[2] / 2;        // 1000000

  u16*   aggh = (u16*)d_ws;
  u32*   pk3  = (u32*)(aggh + (size_t)N * WIDTH);    // N*192 u32
  u16*   pb16 = (u16*)(pk3 + (size_t)N * 192);
  u16*   gembh= pb16 + ARENA_PAD;
  float* gsums= (float*)(gembh + 33 * WIDTH);
  int*   cnt  = (int*)(gsums + 256);
  int*   off  = cnt + N;
  int*   bsum = off + N;
  uint2* sedge= (uint2*)(bsum + 1024);
  u32*   h1d  = (u32*)d_out;            // N*64 u32 f16-pairs; overwritten by k_post

  const int nbc = (OFF_WGC + N + 255) / 256;
  const int nbh = (E + 255) / 256;      // 3907

  hipMemsetAsync(cnt, 0, (size_t)N * sizeof(int), stream);

  k_init_hist<<<nbh + nbc + 147, 256, 0, stream>>>(
      d_in[4], d_in[5], d_in[6], d_in[7], d_in[8], d_in[9], d_in[10],
      d_in[11], d_in[12], d_in[13], deg, eidx, cnt, E, pb16, gembh, gsums, N);

  const int npre = N / 64;              // 3125
  const int nblk = (N + 1023) / 1024;   // 196
  k_pre_scan1<<<npre + nblk, 512, 0, stream>>>(
      x, pb16, pk3, h1d, deg, cnt, bsum, N, npre);

  k_scan3  <<<nblk, 256, 0, stream>>>(cnt, bsum, off, N);
  k_scatter<<<nbh, 256, 0, stream>>>(eidx, eattr, off, sedge, E);

  k_agg<<<((size_t)N * 16 + 255) / 256, 256, 0, stream>>>(
      pk3, h1d, sedge, off, pb16, (const u32*)gembh, gsums, aggh, N);

  k_post<<<N / 64, 256, 0, stream>>>(aggh, pb16, d_out, deg);
}

// Round 8
// 671.595 us; speedup vs baseline: 1.0957x; 1.0957x over previous
//
#include <hip/hip_runtime.h>
#include <hip/hip_bf16.h>
#include <hip/hip_fp16.h>

// MetaGIN round 12: exact R10 structure (measured: total 668, k_agg 198) with
// ONE change: k_agg's DSTEP conv weights staged in LDS (per-lane padded rows,
// 33-dword stride -> conflict-free ds_read_b32 @ immediate offsets), killing
// the compiler's per-dst global weight reloads (VGPR=40 proved arrays were
// rematerialized as 32 scattered loads per dst-group).
//
// chain: memset ; k_init_hist ; k_pre_scan1 ; k_scan3 ; k_scatter ; k_agg ;
//        k_post.
// ws layout: aggh N*128 f16 | h1 N*64 u32 | pk0ab N*128 u32 | pb16 arena |
//            gembh 33*128 f16 | gsums 256 f32 | cnt N | off N | bsum 1024 |
//            sedge E uint2   (~215 MB)
// uv0 (N*64 u32 f16-pairs) lives in d_out (fully overwritten by k_post).

typedef unsigned short u16;
typedef unsigned int   u32;

#define WIDTH 128

// params arena element offsets (bf16 except GW/VW/PW/WGC/WVC/BGC/BVC = f16)
#define OFF_W0   0        // 16384
#define OFF_B0   16384    // 128
#define OFF_W1   16512    // 16384
#define OFF_B1   32896    // 128
#define OFF_EMB  33024    // 33*128 = 4224
#define OFF_GW   37248    // 128*16 = 2048 (f16)
#define OFF_VW   39296    // 2048 (f16)
#define OFF_PW   41344    // 16384 (f16)
#define OFF_PB   57728    // 128
#define OFF_DP   57856    // 128
#define OFF_WGC  57984    // 16384 (f16)  composite G.W0
#define OFF_WVC  74368    // 16384 (f16)  composite V.W0
#define OFF_BGC  90752    // 128 (f16)    composite G.b0
#define OFF_BVC  90880    // 128 (f16)    composite V.b0
#define OFF_DEG  91008    // N (bf16)
#define ARENA_PAD 291072  // u16 elems (>= OFF_DEG+N, even)

typedef __attribute__((ext_vector_type(8))) short bf16x8;
typedef __attribute__((ext_vector_type(8))) _Float16 f16x8;
typedef __attribute__((ext_vector_type(4))) float f32x4;
typedef __attribute__((ext_vector_type(2))) __fp16 f16x2;

__device__ __forceinline__ float b2f(u16 u){ return __uint_as_float(((u32)u) << 16); }
__device__ __forceinline__ u16   f2b(float f){
  u32 u = __float_as_uint(f);
  u += 0x7fffu + ((u >> 16) & 1u);   // RNE
  return (u16)(u >> 16);
}
__device__ __forceinline__ u16   f2h(float f){ return __half_as_ushort(__float2half(f)); }
__device__ __forceinline__ float h2f(u16 u){ return __half2float(__ushort_as_half(u)); }

__device__ __forceinline__ f16x2 u2h(u32 u){ union { u32 a; f16x2 b; } c; c.a = u; return c.b; }
__device__ __forceinline__ u32   h2u(f16x2 h){ union { f16x2 b; u32 a; } c; c.b = h; return c.a; }

__device__ __forceinline__ f16x2 pkhfma(f16x2 a, f16x2 b, f16x2 c){
#if __has_builtin(__builtin_elementwise_fma)
  return __builtin_elementwise_fma(a, b, c);
#else
  return a * b + c;
#endif
}

// s += dpp_xlane(s); 0xB1=quad_perm xor1, 0x4E=quad_perm xor2,
// 0x141=row_half_mirror (xor7 within 8) -> full 8-lane butterfly in VALU.
#define DPPADD(s, ctrl) {                                                  \
  const float _t = __uint_as_float((u32)__builtin_amdgcn_update_dpp(       \
      0, (int)__float_as_uint(s), (ctrl), 0xF, 0xF, true));                \
  (s) += _t; }

__device__ __forceinline__ bool is_fp32(const void* degsrc){
  // deg = exact ints 1..7: fp32 word0 low16 == 0; bf16 word0 low16 != 0
  return ((*(const u32*)degsrc) & 0xffffu) == 0u;
}

__device__ __forceinline__ bf16x8 cvt8(float4 a, float4 b){
  bf16x8 r;
  r[0]=(short)f2b(a.x); r[1]=(short)f2b(a.y); r[2]=(short)f2b(a.z); r[3]=(short)f2b(a.w);
  r[4]=(short)f2b(b.x); r[5]=(short)f2b(b.y); r[6]=(short)f2b(b.z); r[7]=(short)f2b(b.w);
  return r;
}
__device__ __forceinline__ f16x8 cvt8h(float4 a, float4 b){
  f16x8 r;
  r[0]=(_Float16)a.x; r[1]=(_Float16)a.y; r[2]=(_Float16)a.z; r[3]=(_Float16)a.w;
  r[4]=(_Float16)b.x; r[5]=(_Float16)b.y; r[6]=(_Float16)b.z; r[7]=(_Float16)b.w;
  return r;
}
__device__ __forceinline__ f16x8 cvtbh(bf16x8 v){
  f16x8 r;
  #pragma unroll
  for (int j = 0; j < 8; ++j) r[j] = (_Float16)b2f((u16)v[j]);
  return r;
}

__device__ __forceinline__ u16 cvt_one(const void* src, int j, bool f32){
  return f32 ? f2b(((const float*)src)[j]) : ((const u16*)src)[j];
}
__device__ __forceinline__ u16 cvt_one_h(const void* src, int j, bool f32){
  return f32 ? f2h(((const float*)src)[j]) : f2h(b2f(((const u16*)src)[j]));
}
__device__ __forceinline__ float read_f(const void* src, int j, bool f32){
  return f32 ? ((const float*)src)[j] : b2f(((const u16*)src)[j]);
}

// ---------------------------------------------------------------------------
// k_init_hist: {degree histogram | convert params+deg | gemb(f16) | gsums |
// composite W0 weights/biases}. cnt pre-zeroed via hipMemsetAsync.
// ---------------------------------------------------------------------------
__global__ void k_init_hist(const void* w0, const void* b0, const void* w1, const void* b1,
                            const void* emb, const void* gw, const void* vw,
                            const void* pw, const void* pb, const void* dp,
                            const void* degsrc, const int* __restrict__ eidx,
                            int* __restrict__ cnt, int E,
                            u16* __restrict__ pb16, u16* __restrict__ gembh,
                            float* __restrict__ gsums, int N)
{
  const bool f32 = is_fp32(degsrc);
  const int nbh = (E + 255) >> 8;
  const int tot_cvt = OFF_WGC + N;
  const int nbc = (tot_cvt + 255) >> 8;
  int b = blockIdx.x;
  const int t = threadIdx.x;

  if (b < nbh) {                       // degree histogram
    const int e = b * 256 + t;
    if (e < E) atomicAdd(&cnt[eidx[E + e]], 1);
    return;
  }
  b -= nbh;
  if (b < nbc) {                       // convert params (+deg)
    const int i = b * 256 + t;
    if (i >= tot_cvt) return;
    u16 v; int dsti = i;
    if      (i < OFF_B0 ) v = cvt_one(w0,  i,           f32);
    else if (i < OFF_W1 ) v = cvt_one(b0,  i - OFF_B0,  f32);
    else if (i < OFF_B1 ) v = cvt_one(w1,  i - OFF_W1,  f32);
    else if (i < OFF_EMB) v = cvt_one(b1,  i - OFF_B1,  f32);
    else if (i < OFF_GW ) v = cvt_one(emb, i - OFF_EMB, f32);
    else if (i < OFF_VW ) v = cvt_one_h(gw, i - OFF_GW, f32);   // f16
    else if (i < OFF_PW ) v = cvt_one_h(vw, i - OFF_VW, f32);   // f16
    else if (i < OFF_PB ) v = cvt_one_h(pw, i - OFF_PW, f32);   // f16
    else if (i < OFF_DP ) v = cvt_one(pb,  i - OFF_PB,  f32);
    else if (i < OFF_WGC) v = cvt_one(dp,  i - OFF_DP,  f32);
    else { v = cvt_one(degsrc, i - OFF_WGC, f32); dsti = OFF_DEG + (i - OFF_WGC); }
    pb16[dsti] = v;
    return;
  }
  b -= nbc;
  if (b < 17) {                        // gemb (f16): gemb[a][c] = G[c].emb[a]
    const int tid = b * 256 + t;
    if (tid >= 33 * 128) return;
    const int a = tid >> 7, c = tid & 127, g = c >> 4;
    float s = 0.f;
    #pragma unroll
    for (int i = 0; i < 16; ++i)
      s += read_f(gw, c * 16 + i, f32) * read_f(emb, a * WIDTH + g * 16 + i, f32);
    gembh[tid] = f2h(s);
    return;
  }
  b -= 17;
  if (b < 1) {                         // gsums: [0,128)=rowsum(gw), [128,256)=rowsum(vw)
    if (t < 256) {
      const int c = t & 127;
      const void* src = (t >> 7) ? vw : gw;
      float s = 0.f;
      #pragma unroll
      for (int i = 0; i < 16; ++i) s += read_f(src, c * 16 + i, f32);
      gsums[t] = s;
    }
    return;
  }
  b -= 1;
  if (b < 128) {                       // composite weights: (G|V).W0 -> f16
    const int tid = b * 256 + t;      // 0..32767
    const int m = tid >> 14;          // 0: gate, 1: value
    const int o = (tid >> 7) & 127;
    const int i = tid & 127;
    const void* wsel = m ? vw : gw;
    const int hb = (o >> 4) * 16;
    float s = 0.f;
    #pragma unroll
    for (int j = 0; j < 16; ++j)
      s += read_f(wsel, o * 16 + j, f32) * read_f(w0, (size_t)(hb + j) * 128 + i, f32);
    pb16[(m ? OFF_WVC : OFF_WGC) + o * 128 + i] = f2h(s);
    return;
  }
  // composite biases: (G|V).b0 -> f16
  if (t < 256) {
    const int m = t >> 7, o = t & 127, hb = (o >> 4) * 16;
    const void* wsel = m ? vw : gw;
    float s = 0.f;
    #pragma unroll
    for (int j = 0; j < 16; ++j)
      s += read_f(wsel, o * 16 + j, f32) * read_f(b0, hb + j, f32);
    pb16[(m ? OFF_BVC : OFF_BGC) + o] = f2h(s);
  }
}

// ---------------------------------------------------------------------------
// k_pre_scan1: 512 threads. Blocks [0,npre): 8 warps = 4 mats x 2 ch-halves
// over a 64-node tile. mats: 0=h0(W0,bf16)->pk0ab slot0, 1=ug0(G.W0,f16)->
// pk0ab slot1, 2=uv0(V.W0,f16)->d_out, 3=h1(W1,bf16)->h1. Even/odd fragment
// pair-trick -> lane owns adjacent channel pair -> cvt_pkrtz + dword stores.
// Blocks [npre,..): scan1 block sums (needs hist done).
// ---------------------------------------------------------------------------
__global__ __launch_bounds__(512, 2) void k_pre_scan1(
    const void* __restrict__ x, const u16* __restrict__ pb16,
    u32* __restrict__ pk0ab, u32* __restrict__ uv0d, u32* __restrict__ h1d,
    const void* __restrict__ degsrc,
    const int* __restrict__ cnt, int* __restrict__ bsum, int n, int npre)
{
  if ((int)blockIdx.x >= npre) {       // scan1: 1024 elems, 2 per thread
    const int t = threadIdx.x, b = (int)blockIdx.x - npre;
    const int i0 = b * 1024 + t * 2;
    int s = 0;
    if (i0     < n) s += cnt[i0];
    if (i0 + 1 < n) s += cnt[i0 + 1];
    __shared__ int sb[512];
    sb[t] = s; __syncthreads();
    for (int d = 256; d > 0; d >>= 1) { if (t < d) sb[t] += sb[t + d]; __syncthreads(); }
    if (t == 0) bsum[b] = sb[0];
    return;
  }

  const int t = threadIdx.x;
  const int lane = t & 63, lid = lane & 15, quad = lane >> 4;
  const int w = t >> 6, mat = w >> 1, c0 = (w & 1) * 64;
  const int node0 = blockIdx.x * 64;
  const bool f32 = is_fp32(degsrc);
  const bool hp16 = (mat == 1) || (mat == 2);   // f16 composite path

  const u16* wsrc; const u16* bsv;
  u32* outp; int slot = 0; bool pkmode = false;
  if      (mat == 0) { wsrc = pb16 + OFF_W0;  bsv = pb16 + OFF_B0;  outp = pk0ab; slot = 0; pkmode = true; }
  else if (mat == 1) { wsrc = pb16 + OFF_WGC; bsv = pb16 + OFF_BGC; outp = pk0ab; slot = 1; pkmode = true; }
  else if (mat == 2) { wsrc = pb16 + OFF_WVC; bsv = pb16 + OFF_BVC; outp = uv0d; }
  else               { wsrc = pb16 + OFF_W1;  bsv = pb16 + OFF_B1;  outp = h1d; }

  float bias[2][2];
  #pragma unroll
  for (int ntp = 0; ntp < 2; ++ntp)
    #pragma unroll
    for (int eo = 0; eo < 2; ++eo) {
      const u16 braw = bsv[c0 + ntp * 32 + 2 * lid + eo];
      bias[ntp][eo] = hp16 ? h2f(braw) : b2f(braw);
    }

  f32x4 acc[4][2][2];
  #pragma unroll
  for (int mt = 0; mt < 4; ++mt)
    #pragma unroll
    for (int ntp = 0; ntp < 2; ++ntp)
      #pragma unroll
      for (int eo = 0; eo < 2; ++eo)
        #pragma unroll
        for (int r = 0; r < 4; ++r) acc[mt][ntp][eo][r] = bias[ntp][eo];

  if (!hp16) {         // bf16 path
    #pragma unroll
    for (int ks = 0; ks < 4; ++ks) {
      bf16x8 a[4], bb[2][2];
      #pragma unroll
      for (int ntp = 0; ntp < 2; ++ntp)
        #pragma unroll
        for (int eo = 0; eo < 2; ++eo)
          bb[ntp][eo] = *(const bf16x8*)(wsrc +
              (size_t)(c0 + ntp * 32 + 2 * lid + eo) * WIDTH + ks * 32 + quad * 8);
      if (f32) {
        #pragma unroll
        for (int mt = 0; mt < 4; ++mt) {
          const float4* xr = (const float4*)((const float*)x +
              (size_t)(node0 + mt * 16 + lid) * WIDTH + ks * 32 + quad * 8);
          a[mt] = cvt8(xr[0], xr[1]);
        }
      } else {
        #pragma unroll
        for (int mt = 0; mt < 4; ++mt)
          a[mt] = *(const bf16x8*)((const u16*)x +
              (size_t)(node0 + mt * 16 + lid) * WIDTH + ks * 32 + quad * 8);
      }
      #pragma unroll
      for (int mt = 0; mt < 4; ++mt)
        #pragma unroll
        for (int ntp = 0; ntp < 2; ++ntp)
          #pragma unroll
          for (int eo = 0; eo < 2; ++eo)
            acc[mt][ntp][eo] = __builtin_amdgcn_mfma_f32_16x16x32_bf16(
                a[mt], bb[ntp][eo], acc[mt][ntp][eo], 0, 0, 0);
    }
  } else {             // f16 composite path
    #pragma unroll
    for (int ks = 0; ks < 4; ++ks) {
      f16x8 a[4], bb[2][2];
      #pragma unroll
      for (int ntp = 0; ntp < 2; ++ntp)
        #pragma unroll
        for (int eo = 0; eo < 2; ++eo)
          bb[ntp][eo] = *(const f16x8*)(wsrc +
              (size_t)(c0 + ntp * 32 + 2 * lid + eo) * WIDTH + ks * 32 + quad * 8);
      if (f32) {
        #pragma unroll
        for (int mt = 0; mt < 4; ++mt) {
          const float4* xr = (const float4*)((const float*)x +
              (size_t)(node0 + mt * 16 + lid) * WIDTH + ks * 32 + quad * 8);
          a[mt] = cvt8h(xr[0], xr[1]);
        }
      } else {
        #pragma unroll
        for (int mt = 0; mt < 4; ++mt)
          a[mt] = cvtbh(*(const bf16x8*)((const u16*)x +
              (size_t)(node0 + mt * 16 + lid) * WIDTH + ks * 32 + quad * 8));
      }
      #pragma unroll
      for (int mt = 0; mt < 4; ++mt)
        #pragma unroll
        for (int ntp = 0; ntp < 2; ++ntp)
          #pragma unroll
          for (int eo = 0; eo < 2; ++eo)
            acc[mt][ntp][eo] = __builtin_amdgcn_mfma_f32_16x16x32_f16(
                a[mt], bb[ntp][eo], acc[mt][ntp][eo], 0, 0, 0);
    }
  }

  // epilogue: adjacent-pair pack, dword stores
  #pragma unroll
  for (int mt = 0; mt < 4; ++mt)
    #pragma unroll
    for (int r = 0; r < 4; ++r) {
      const int node = node0 + mt * 16 + quad * 4 + r;
      #pragma unroll
      for (int ntp = 0; ntp < 2; ++ntp) {
        const int p = (c0 >> 1) + ntp * 16 + lid;
        const u32 pk = h2u(__builtin_amdgcn_cvt_pkrtz(
            acc[mt][ntp][0][r], acc[mt][ntp][1][r]));
        if (pkmode) outp[(size_t)node * 128 + p * 2 + slot] = pk;
        else        outp[(size_t)node * 64 + p] = pk;
      }
    }
}

// ---------------------------------------------------------------------------
// k_scan3: full exclusive scan (folds scan2's bsum prefix in per block).
// ---------------------------------------------------------------------------
__global__ void k_scan3(const int* __restrict__ cnt, const int* __restrict__ bsum,
                        int* __restrict__ off, int n){
  const int t = threadIdx.x, b = blockIdx.x;
  __shared__ int sp[256];
  int pv = 0;
  for (int j = t; j < b; j += 256) pv += bsum[j];
  sp[t] = pv; __syncthreads();
  for (int d = 128; d > 0; d >>= 1) { if (t < d) sp[t] += sp[t + d]; __syncthreads(); }
  const int bpref = sp[0];

  const int i0 = b * 1024 + t * 4;
  int c[4];
  #pragma unroll
  for (int j = 0; j < 4; ++j) { int i = i0 + j; c[j] = (i < n) ? cnt[i] : 0; }
  int tsum = c[0] + c[1] + c[2] + c[3];
  __shared__ int sb[256];
  sb[t] = tsum; __syncthreads();
  for (int d = 1; d < 256; d <<= 1) {
    int x = (t >= d) ? sb[t - d] : 0;
    __syncthreads();
    sb[t] += x;
    __syncthreads();
  }
  int run = bpref + sb[t] - tsum;
  #pragma unroll
  for (int j = 0; j < 4; ++j) {
    int i = i0 + j;
    if (i < n) off[i] = run;
    run += c[j];
  }
}

// scatter edges into dst-sorted order; one 8B store per edge; cb at bits 18-19.
// off[dst] becomes END pointer after this.
__global__ void k_scatter(const int* __restrict__ eidx, const int* __restrict__ eattr,
                          int* __restrict__ off, uint2* __restrict__ sedge, int E){
  const int e = blockIdx.x * 256 + threadIdx.x;
  if (e >= E) return;
  const int dst = eidx[E + e];
  const int pos = atomicAdd(&off[dst], 1);
  const u32 a0 = (u32)eattr[e*3+0], a1 = (u32)eattr[e*3+1], a2 = (u32)eattr[e*3+2];
  u32 cb = (a0 != 0) + (a1 != 0) + (a2 != 0);
  cb = cb ? cb : 1u;
  sedge[pos] = make_uint2((u32)eidx[e], a0 | (a1 << 6) | (a2 << 12) | (cb << 18));
}

// ---------------------------------------------------------------------------
// k_agg: one wave per 4 consecutive dst nodes. Lane q owns channels
// {2q,2q+1}; 8-lane clusters = one 16-ch head. gemb AND conv weights in LDS
// (weights re-laid per-lane, 33-dword padded rows -> conflict-free ds_read
// with immediate offsets; kills per-dst global weight reloads).
// Per dst:  DSTEP swizzle conv of h1 row (ug1/uv1), pk_fma_f16, LDS weights.
// Per edge: dwordx2 pk0ab + dword uv0 + 3 ds_read gemb; DPP stats.
// ---------------------------------------------------------------------------
__global__ __launch_bounds__(256, 6) void k_agg(
    const u32* __restrict__ pk32, const u32* __restrict__ uv32,
    const u16* __restrict__ h1, const uint2* __restrict__ sedge,
    const int* __restrict__ off, const u16* __restrict__ pb16,
    const u32* __restrict__ gembw, const float* __restrict__ gsums,
    u16* __restrict__ aggh, const int N)
{
  __shared__ u32 gl[2112];             // gemb f16[33][128] as u32 pairs
  __shared__ u32 wL[64 * 33];          // per-lane conv weights, padded rows
  for (int j = threadIdx.x; j < 2112; j += 256) gl[j] = gembw[j];
  {
    const u32* gwp = (const u32*)(pb16 + OFF_GW);
    const u32* vwp = (const u32*)(pb16 + OFF_VW);
    for (int j = threadIdx.x; j < 2048; j += 256) {
      const int qq = j >> 5, k = j & 31;
      const u32 v = (k < 16) ? gwp[qq * 16 + k] : vwp[qq * 16 + (k & 15)];
      wL[qq * 33 + k] = v;             // [0..7]=gw0 [8..15]=gw1 [16..23]=vw0 [24..31]=vw1
    }
  }
  __syncthreads();

  const int base = ((blockIdx.x * 256 + threadIdx.x) >> 6) * 4;
  if (base >= N) return;
  const int q = threadIdx.x & 63;
  const int c0 = 2 * q;           // my channels: c0, c0+1
  const u32* wme = wL + q * 33;   // my 32 packed weight words

  const float gs0 = gsums[c0],       gs1 = gsums[c0 + 1];
  const float vs0 = gsums[128 + c0], vs1 = gsums[128 + c0 + 1];

  u32 h1w[4]; int nend[4];
  #pragma unroll
  for (int d = 0; d < 4; ++d) {
    const int dst = min(base + d, N - 1);
    h1w[d]  = *(const u32*)(h1 + (size_t)dst * WIDTH + c0);
    nend[d] = off[dst];
  }
  int ncur = base ? off[base - 1] : 0;
  const int nlast = nend[3];

  // pipeline: edn = descriptor for edge i+1; payload regs for edge i
  u32 hp = 0, ugp = 0, uvp = 0, g0w = 0, g1w = 0, g2w = 0; float pinv = 1.f;
  uint2 edn = make_uint2(0u, 0u);
  if (ncur < nlast) {
    const uint2 e0 = sedge[ncur];
    edn = sedge[min(ncur + 1, nlast - 1)];
    const u32 po = e0.x * 128u + (u32)(q * 2);
    hp  = pk32[po];
    ugp = pk32[po + 1];
    uvp = uv32[e0.x * 64u + (u32)q];
    const int a0 = e0.y & 63, a1 = (e0.y >> 6) & 63, a2 = (e0.y >> 12) & 63;
    g0w = gl[a0 * 64 + q];
    g1w = gl[a1 * 64 + q];
    g2w = gl[a2 * 64 + q];
    pinv = __builtin_amdgcn_rcpf((float)((e0.y >> 18) & 3));
  }

  #pragma unroll
  for (int d = 0; d < 4; ++d) {
    const f16x2 h1h = u2h(h1w[d]);

    // per-dst grouped conv of h1 row: LDS weights @ immediate offsets
    f16x2 ag0 = u2h(0), ag1 = u2h(0), av0 = u2h(0), av1 = u2h(0);
#define DSTEP(J) {                                                             \
    const f16x2 xj = u2h((u32)__builtin_amdgcn_ds_swizzle(                     \
        (int)h1w[d], 0x18 | ((J) << 5)));                                      \
    ag0 = pkhfma(xj, u2h(wme[(J)]),      ag0);                                 \
    ag1 = pkhfma(xj, u2h(wme[8 + (J)]),  ag1);                                 \
    av0 = pkhfma(xj, u2h(wme[16 + (J)]), av0);                                 \
    av1 = pkhfma(xj, u2h(wme[24 + (J)]), av1); }
    DSTEP(0) DSTEP(1) DSTEP(2) DSTEP(3) DSTEP(4) DSTEP(5) DSTEP(6) DSTEP(7)
#undef DSTEP
    const float ug1d0 = (float)ag0.x + (float)ag0.y;
    const float ug1d1 = (float)ag1.x + (float)ag1.y;
    const float uv1d0 = (float)av0.x + (float)av0.y;
    const float uv1d1 = (float)av1.x + (float)av1.y;

    const int n1 = nend[d];
    float acc0 = 0.f, acc1 = 0.f;

    for (int i = ncur; i < n1; ++i) {
      const u32 hp_c = hp, ug_c = ugp, uv_c = uvp;
      const u32 g0c = g0w, g1c = g1w, g2c = g2w;
      const float inv_c = pinv;
      {                                     // prefetch payload for i+1
        const uint2 en = edn;
        edn = sedge[min(i + 2, nlast - 1)]; // descriptor 2 ahead
        const u32 po = en.x * 128u + (u32)(q * 2);
        hp  = pk32[po];
        ugp = pk32[po + 1];
        uvp = uv32[en.x * 64u + (u32)q];
        const int a0 = en.y & 63, a1 = (en.y >> 6) & 63, a2 = (en.y >> 12) & 63;
        g0w = gl[a0 * 64 + q];
        g1w = gl[a1 * 64 + q];
        g2w = gl[a2 * 64 + q];
        pinv = __builtin_amdgcn_rcpf((float)((en.y >> 18) & 3));
      }

      // x = h0[src] + h1[dst], packed f16 (raw, un-normalized)
      const f16x2 xh = u2h(hp_c) + h1h;
      const float x0 = (float)xh.x, x1 = (float)xh.y;

      // stats over 16-ch head via DPP butterfly
      float s  = x0 + x1;
      float ss = fmaf(x0, x0, x1 * x1);
      DPPADD(s, 0xB1);  DPPADD(ss, 0xB1);
      DPPADD(s, 0x4E);  DPPADD(ss, 0x4E);
      DPPADD(s, 0x141); DPPADD(ss, 0x141);
      const float mean = s * 0.0625f;
      const float var  = fmaf(ss, 0.0625f, -mean * mean);
      const float rs   = __builtin_amdgcn_rsqf(var + 1e-5f);
      const float mrs  = mean * rs;

      // bag (pre-projected through gate weights), f16 sum then scale
      const f16x2 bsum3 = u2h(g0c) + u2h(g1c) + u2h(g2c);
      const float bg0 = (float)bsum3.x * inv_c;
      const float bg1 = (float)bsum3.y * inv_c;

      // gate = rs*(ug0+ug1) - mrs*gsum + bag ; val = rs*(uv0+uv1) - mrs*vsum
      const f16x2 ugh = u2h(ug_c), uvh = u2h(uv_c);
      const float gate0 = fmaf(rs, (float)ugh.x + ug1d0, fmaf(-mrs, gs0, bg0));
      const float gate1 = fmaf(rs, (float)ugh.y + ug1d1, fmaf(-mrs, gs1, bg1));
      const float val0  = fmaf(rs, (float)uvh.x + uv1d0, -mrs * vs0);
      const float val1  = fmaf(rs, (float)uvh.y + uv1d1, -mrs * vs1);
      acc0 = fmaf(fmaxf(gate0, 0.f), val0, acc0);
      acc1 = fmaf(fmaxf(gate1, 0.f), val1, acc1);
    }

    if (base + d < N)
      *(u32*)(aggh + (size_t)(base + d) * WIDTH + c0) =
          h2u(__builtin_amdgcn_cvt_pkrtz(acc0, acc1));
    ncur = n1;
  }
}

// ---------------------------------------------------------------------------
// k_post: out = (agg @ pw^T + pb) * deg^dp via f16 MFMA (agg & pw are f16).
// ---------------------------------------------------------------------------
__global__ __launch_bounds__(256, 2) void k_post(
    const u16* __restrict__ aggh, const u16* __restrict__ pb16,
    void* __restrict__ out, const void* __restrict__ degsrc)
{
  const int t = threadIdx.x;
  const int lane = t & 63, lid = lane & 15, quad = lane >> 4;
  const int w = t >> 6, c0 = (w & 1) * 64, mh = (w >> 1) * 32;
  const int node0 = blockIdx.x * 64;
  const bool f32o = is_fp32(degsrc);

  f32x4 acc[2][4];
  float dpc[4];
  #pragma unroll
  for (int nt = 0; nt < 4; ++nt) {
    const float bias = b2f(pb16[OFF_PB + c0 + nt * 16 + lid]);
    dpc[nt] = b2f(pb16[OFF_DP + c0 + nt * 16 + lid]);
    #pragma unroll
    for (int mt = 0; mt < 2; ++mt)
      #pragma unroll
      for (int r = 0; r < 4; ++r) acc[mt][nt][r] = bias;
  }

  #pragma unroll
  for (int ks = 0; ks < 4; ++ks) {
    f16x8 a[2], b[4];
    #pragma unroll
    for (int nt = 0; nt < 4; ++nt)
      b[nt] = *(const f16x8*)(pb16 + OFF_PW + (size_t)(c0 + nt * 16 + lid) * WIDTH + ks * 32 + quad * 8);
    #pragma unroll
    for (int mt = 0; mt < 2; ++mt)
      a[mt] = *(const f16x8*)(aggh +
          (size_t)(node0 + mh + mt * 16 + lid) * WIDTH + ks * 32 + quad * 8);
    #pragma unroll
    for (int mt = 0; mt < 2; ++mt)
      #pragma unroll
      for (int nt = 0; nt < 4; ++nt)
        acc[mt][nt] = __builtin_amdgcn_mfma_f32_16x16x32_f16(a[mt], b[nt], acc[mt][nt], 0, 0, 0);
  }

  float logd[2][4];
  #pragma unroll
  for (int mt = 0; mt < 2; ++mt)
    #pragma unroll
    for (int r = 0; r < 4; ++r)
      logd[mt][r] = __logf(b2f(pb16[OFF_DEG + node0 + mh + mt * 16 + quad * 4 + r]));

  #pragma unroll
  for (int mt = 0; mt < 2; ++mt)
    #pragma unroll
    for (int nt = 0; nt < 4; ++nt)
      #pragma unroll
      for (int r = 0; r < 4; ++r) {
        const int node = node0 + mh + mt * 16 + quad * 4 + r;
        const float v = acc[mt][nt][r] * __expf(dpc[nt] * logd[mt][r]);
        if (f32o) ((float*)out)[(size_t)node * WIDTH + c0 + nt * 16 + lid] = v;
        else      ((u16*)out)[(size_t)node * WIDTH + c0 + nt * 16 + lid] = f2b(v);
      }
}

extern "C" void kernel_launch(void* const* d_in, const int* in_sizes, int n_in,
                              void* d_out, int out_size, void* d_ws, size_t ws_size,
                              hipStream_t stream)
{
  (void)n_in; (void)out_size; (void)ws_size;
  const void* x     = d_in[0];
  const void* deg   = d_in[1];
  const int*  eidx  = (const int*)d_in[2];
  const int*  eattr = (const int*)d_in[3];

  const int N = in_sizes[1];            // 200000
  const int E = in_sizes[2] / 2;        // 1000000

  u16*   aggh = (u16*)d_ws;
  u16*   h1   = aggh + (size_t)N * WIDTH;
  u32*   pk0ab= (u32*)(h1 + (size_t)N * WIDTH);      // N*128 u32
  u16*   pb16 = (u16*)(pk0ab + (size_t)N * 128);
  u16*   gembh= pb16 + ARENA_PAD;
  float* gsums= (float*)(gembh + 33 * WIDTH);
  int*   cnt  = (int*)(gsums + 256);
  int*   off  = cnt + N;
  int*   bsum = off + N;
  uint2* sedge= (uint2*)(bsum + 1024);
  u32*   uv0d = (u32*)d_out;            // N*64 u32 f16-pairs; overwritten by k_post

  const int nbc = (OFF_WGC + N + 255) / 256;
  const int nbh = (E + 255) / 256;      // 3907

  hipMemsetAsync(cnt, 0, (size_t)N * sizeof(int), stream);

  k_init_hist<<<nbh + nbc + 147, 256, 0, stream>>>(
      d_in[4], d_in[5], d_in[6], d_in[7], d_in[8], d_in[9], d_in[10],
      d_in[11], d_in[12], d_in[13], deg, eidx, cnt, E, pb16, gembh, gsums, N);

  const int npre = N / 64;              // 3125
  const int nblk = (N + 1023) / 1024;   // 196
  k_pre_scan1<<<npre + nblk, 512, 0, stream>>>(
      x, pb16, pk0ab, uv0d, (u32*)h1, deg, cnt, bsum, N, npre);

  k_scan3  <<<nblk, 256, 0, stream>>>(cnt, bsum, off, N);
  k_scatter<<<nbh, 256, 0, stream>>>(eidx, eattr, off, sedge, E);

  k_agg<<<((size_t)N * 16 + 255) / 256, 256, 0, stream>>>(
      pk0ab, uv0d, h1, sedge, off, pb16, (const u32*)gembh, gsums, aggh, N);

  k_post<<<N / 64, 256, 0, stream>>>(aggh, pb16, d_out, deg);
}

// Round 9
// 666.215 us; speedup vs baseline: 1.1045x; 1.0081x over previous
//
#include <hip/hip_runtime.h>
#include <hip/hip_bf16.h>
#include <hip/hip_fp16.h>

// MetaGIN round 13: R12 base (measured: total 671, k_agg 197) + two changes:
//  - pk3 plane-major payload [node][plane][64 dwords]: planes {h0,ug0,uv0}.
//    k_pre stores stay stride-1 coalesced (R11's failure was stride-3
//    interleave); k_agg gathers with ONE address chain + imm offsets
//    0/256/512B. h1 (per-dst stream) lives in d_out.
//  - k_agg stats butterfly via ds_swizzle (LDS pipe) instead of DPP (VALU):
//    6 swizzle + 6 add replaces 12 VALU instrs; we are VALU-issue-bound.
//
// chain: memset ; k_init_hist ; k_pre_scan1 ; k_scan3 ; k_scatter ; k_agg ;
//        k_post.
// ws layout: aggh N*128 f16 | pk3 N*192 u32 | pb16 arena | gembh 33*128 f16 |
//            gsums 256 f32 | cnt N | off N | bsum 1024 | sedge E uint2 (~215MB)
// h1 (N*64 u32 f16-pairs) lives in d_out (fully overwritten by k_post).

typedef unsigned short u16;
typedef unsigned int   u32;

#define WIDTH 128

// params arena element offsets (bf16 except GW/VW/PW/WGC/WVC/BGC/BVC = f16)
#define OFF_W0   0        // 16384
#define OFF_B0   16384    // 128
#define OFF_W1   16512    // 16384
#define OFF_B1   32896    // 128
#define OFF_EMB  33024    // 33*128 = 4224
#define OFF_GW   37248    // 128*16 = 2048 (f16)
#define OFF_VW   39296    // 2048 (f16)
#define OFF_PW   41344    // 16384 (f16)
#define OFF_PB   57728    // 128
#define OFF_DP   57856    // 128
#define OFF_WGC  57984    // 16384 (f16)  composite G.W0
#define OFF_WVC  74368    // 16384 (f16)  composite V.W0
#define OFF_BGC  90752    // 128 (f16)    composite G.b0
#define OFF_BVC  90880    // 128 (f16)    composite V.b0
#define OFF_DEG  91008    // N (bf16)
#define ARENA_PAD 291072  // u16 elems (>= OFF_DEG+N, even)

typedef __attribute__((ext_vector_type(8))) short bf16x8;
typedef __attribute__((ext_vector_type(8))) _Float16 f16x8;
typedef __attribute__((ext_vector_type(4))) float f32x4;
typedef __attribute__((ext_vector_type(2))) __fp16 f16x2;

__device__ __forceinline__ float b2f(u16 u){ return __uint_as_float(((u32)u) << 16); }
__device__ __forceinline__ u16   f2b(float f){
  u32 u = __float_as_uint(f);
  u += 0x7fffu + ((u >> 16) & 1u);   // RNE
  return (u16)(u >> 16);
}
__device__ __forceinline__ u16   f2h(float f){ return __half_as_ushort(__float2half(f)); }
__device__ __forceinline__ float h2f(u16 u){ return __half2float(__ushort_as_half(u)); }

__device__ __forceinline__ f16x2 u2h(u32 u){ union { u32 a; f16x2 b; } c; c.a = u; return c.b; }
__device__ __forceinline__ u32   h2u(f16x2 h){ union { f16x2 b; u32 a; } c; c.b = h; return c.a; }

__device__ __forceinline__ f16x2 pkhfma(f16x2 a, f16x2 b, f16x2 c){
#if __has_builtin(__builtin_elementwise_fma)
  return __builtin_elementwise_fma(a, b, c);
#else
  return a * b + c;
#endif
}

// butterfly-add via ds_swizzle (LDS pipe): xor1/xor2/xor4 within 32-lane group
#define SWZF(v, imm) __uint_as_float((u32)__builtin_amdgcn_ds_swizzle((int)__float_as_uint(v), (imm)))

__device__ __forceinline__ bool is_fp32(const void* degsrc){
  // deg = exact ints 1..7: fp32 word0 low16 == 0; bf16 word0 low16 != 0
  return ((*(const u32*)degsrc) & 0xffffu) == 0u;
}

__device__ __forceinline__ bf16x8 cvt8(float4 a, float4 b){
  bf16x8 r;
  r[0]=(short)f2b(a.x); r[1]=(short)f2b(a.y); r[2]=(short)f2b(a.z); r[3]=(short)f2b(a.w);
  r[4]=(short)f2b(b.x); r[5]=(short)f2b(b.y); r[6]=(short)f2b(b.z); r[7]=(short)f2b(b.w);
  return r;
}
__device__ __forceinline__ f16x8 cvt8h(float4 a, float4 b){
  f16x8 r;
  r[0]=(_Float16)a.x; r[1]=(_Float16)a.y; r[2]=(_Float16)a.z; r[3]=(_Float16)a.w;
  r[4]=(_Float16)b.x; r[5]=(_Float16)b.y; r[6]=(_Float16)b.z; r[7]=(_Float16)b.w;
  return r;
}
__device__ __forceinline__ f16x8 cvtbh(bf16x8 v){
  f16x8 r;
  #pragma unroll
  for (int j = 0; j < 8; ++j) r[j] = (_Float16)b2f((u16)v[j]);
  return r;
}

__device__ __forceinline__ u16 cvt_one(const void* src, int j, bool f32){
  return f32 ? f2b(((const float*)src)[j]) : ((const u16*)src)[j];
}
__device__ __forceinline__ u16 cvt_one_h(const void* src, int j, bool f32){
  return f32 ? f2h(((const float*)src)[j]) : f2h(b2f(((const u16*)src)[j]));
}
__device__ __forceinline__ float read_f(const void* src, int j, bool f32){
  return f32 ? ((const float*)src)[j] : b2f(((const u16*)src)[j]);
}

// ---------------------------------------------------------------------------
// k_init_hist: {degree histogram | convert params+deg | gemb(f16) | gsums |
// composite W0 weights/biases}. cnt pre-zeroed via hipMemsetAsync.
// ---------------------------------------------------------------------------
__global__ void k_init_hist(const void* w0, const void* b0, const void* w1, const void* b1,
                            const void* emb, const void* gw, const void* vw,
                            const void* pw, const void* pb, const void* dp,
                            const void* degsrc, const int* __restrict__ eidx,
                            int* __restrict__ cnt, int E,
                            u16* __restrict__ pb16, u16* __restrict__ gembh,
                            float* __restrict__ gsums, int N)
{
  const bool f32 = is_fp32(degsrc);
  const int nbh = (E + 255) >> 8;
  const int tot_cvt = OFF_WGC + N;
  const int nbc = (tot_cvt + 255) >> 8;
  int b = blockIdx.x;
  const int t = threadIdx.x;

  if (b < nbh) {                       // degree histogram
    const int e = b * 256 + t;
    if (e < E) atomicAdd(&cnt[eidx[E + e]], 1);
    return;
  }
  b -= nbh;
  if (b < nbc) {                       // convert params (+deg)
    const int i = b * 256 + t;
    if (i >= tot_cvt) return;
    u16 v; int dsti = i;
    if      (i < OFF_B0 ) v = cvt_one(w0,  i,           f32);
    else if (i < OFF_W1 ) v = cvt_one(b0,  i - OFF_B0,  f32);
    else if (i < OFF_B1 ) v = cvt_one(w1,  i - OFF_W1,  f32);
    else if (i < OFF_EMB) v = cvt_one(b1,  i - OFF_B1,  f32);
    else if (i < OFF_GW ) v = cvt_one(emb, i - OFF_EMB, f32);
    else if (i < OFF_VW ) v = cvt_one_h(gw, i - OFF_GW, f32);   // f16
    else if (i < OFF_PW ) v = cvt_one_h(vw, i - OFF_VW, f32);   // f16
    else if (i < OFF_PB ) v = cvt_one_h(pw, i - OFF_PW, f32);   // f16
    else if (i < OFF_DP ) v = cvt_one(pb,  i - OFF_PB,  f32);
    else if (i < OFF_WGC) v = cvt_one(dp,  i - OFF_DP,  f32);
    else { v = cvt_one(degsrc, i - OFF_WGC, f32); dsti = OFF_DEG + (i - OFF_WGC); }
    pb16[dsti] = v;
    return;
  }
  b -= nbc;
  if (b < 17) {                        // gemb (f16): gemb[a][c] = G[c].emb[a]
    const int tid = b * 256 + t;
    if (tid >= 33 * 128) return;
    const int a = tid >> 7, c = tid & 127, g = c >> 4;
    float s = 0.f;
    #pragma unroll
    for (int i = 0; i < 16; ++i)
      s += read_f(gw, c * 16 + i, f32) * read_f(emb, a * WIDTH + g * 16 + i, f32);
    gembh[tid] = f2h(s);
    return;
  }
  b -= 17;
  if (b < 1) {                         // gsums: [0,128)=rowsum(gw), [128,256)=rowsum(vw)
    if (t < 256) {
      const int c = t & 127;
      const void* src = (t >> 7) ? vw : gw;
      float s = 0.f;
      #pragma unroll
      for (int i = 0; i < 16; ++i) s += read_f(src, c * 16 + i, f32);
      gsums[t] = s;
    }
    return;
  }
  b -= 1;
  if (b < 128) {                       // composite weights: (G|V).W0 -> f16
    const int tid = b * 256 + t;      // 0..32767
    const int m = tid >> 14;          // 0: gate, 1: value
    const int o = (tid >> 7) & 127;
    const int i = tid & 127;
    const void* wsel = m ? vw : gw;
    const int hb = (o >> 4) * 16;
    float s = 0.f;
    #pragma unroll
    for (int j = 0; j < 16; ++j)
      s += read_f(wsel, o * 16 + j, f32) * read_f(w0, (size_t)(hb + j) * 128 + i, f32);
    pb16[(m ? OFF_WVC : OFF_WGC) + o * 128 + i] = f2h(s);
    return;
  }
  // composite biases: (G|V).b0 -> f16
  if (t < 256) {
    const int m = t >> 7, o = t & 127, hb = (o >> 4) * 16;
    const void* wsel = m ? vw : gw;
    float s = 0.f;
    #pragma unroll
    for (int j = 0; j < 16; ++j)
      s += read_f(wsel, o * 16 + j, f32) * read_f(b0, hb + j, f32);
    pb16[(m ? OFF_BVC : OFF_BGC) + o] = f2h(s);
  }
}

// ---------------------------------------------------------------------------
// k_pre_scan1: 512 threads. Blocks [0,npre): 8 warps = 4 mats x 2 ch-halves
// over a 64-node tile. mats: 0=h0(W0,bf16)->pk3 plane0, 1=ug0(G.W0,f16)->
// plane1, 2=uv0(V.W0,f16)->plane2, 3=h1(W1,bf16)->d_out. Even/odd fragment
// pair-trick -> lane owns adjacent channel pair -> cvt_pkrtz + dword stores
// (stride-1 within each plane -> fully coalesced).
// Blocks [npre,..): scan1 block sums (needs hist done).
// ---------------------------------------------------------------------------
__global__ __launch_bounds__(512, 2) void k_pre_scan1(
    const void* __restrict__ x, const u16* __restrict__ pb16,
    u32* __restrict__ pk3, u32* __restrict__ h1d,
    const void* __restrict__ degsrc,
    const int* __restrict__ cnt, int* __restrict__ bsum, int n, int npre)
{
  if ((int)blockIdx.x >= npre) {       // scan1: 1024 elems, 2 per thread
    const int t = threadIdx.x, b = (int)blockIdx.x - npre;
    const int i0 = b * 1024 + t * 2;
    int s = 0;
    if (i0     < n) s += cnt[i0];
    if (i0 + 1 < n) s += cnt[i0 + 1];
    __shared__ int sb[512];
    sb[t] = s; __syncthreads();
    for (int d = 256; d > 0; d >>= 1) { if (t < d) sb[t] += sb[t + d]; __syncthreads(); }
    if (t == 0) bsum[b] = sb[0];
    return;
  }

  const int t = threadIdx.x;
  const int lane = t & 63, lid = lane & 15, quad = lane >> 4;
  const int w = t >> 6, mat = w >> 1, c0 = (w & 1) * 64;
  const int node0 = blockIdx.x * 64;
  const bool f32 = is_fp32(degsrc);
  const bool hp16 = (mat == 1) || (mat == 2);   // f16 composite path

  const u16* wsrc; const u16* bsv;
  if      (mat == 0) { wsrc = pb16 + OFF_W0;  bsv = pb16 + OFF_B0;  }
  else if (mat == 1) { wsrc = pb16 + OFF_WGC; bsv = pb16 + OFF_BGC; }
  else if (mat == 2) { wsrc = pb16 + OFF_WVC; bsv = pb16 + OFF_BVC; }
  else               { wsrc = pb16 + OFF_W1;  bsv = pb16 + OFF_B1;  }

  float bias[2][2];
  #pragma unroll
  for (int ntp = 0; ntp < 2; ++ntp)
    #pragma unroll
    for (int eo = 0; eo < 2; ++eo) {
      const u16 braw = bsv[c0 + ntp * 32 + 2 * lid + eo];
      bias[ntp][eo] = hp16 ? h2f(braw) : b2f(braw);
    }

  f32x4 acc[4][2][2];
  #pragma unroll
  for (int mt = 0; mt < 4; ++mt)
    #pragma unroll
    for (int ntp = 0; ntp < 2; ++ntp)
      #pragma unroll
      for (int eo = 0; eo < 2; ++eo)
        #pragma unroll
        for (int r = 0; r < 4; ++r) acc[mt][ntp][eo][r] = bias[ntp][eo];

  if (!hp16) {         // bf16 path
    #pragma unroll
    for (int ks = 0; ks < 4; ++ks) {
      bf16x8 a[4], bb[2][2];
      #pragma unroll
      for (int ntp = 0; ntp < 2; ++ntp)
        #pragma unroll
        for (int eo = 0; eo < 2; ++eo)
          bb[ntp][eo] = *(const bf16x8*)(wsrc +
              (size_t)(c0 + ntp * 32 + 2 * lid + eo) * WIDTH + ks * 32 + quad * 8);
      if (f32) {
        #pragma unroll
        for (int mt = 0; mt < 4; ++mt) {
          const float4* xr = (const float4*)((const float*)x +
              (size_t)(node0 + mt * 16 + lid) * WIDTH + ks * 32 + quad * 8);
          a[mt] = cvt8(xr[0], xr[1]);
        }
      } else {
        #pragma unroll
        for (int mt = 0; mt < 4; ++mt)
          a[mt] = *(const bf16x8*)((const u16*)x +
              (size_t)(node0 + mt * 16 + lid) * WIDTH + ks * 32 + quad * 8);
      }
      #pragma unroll
      for (int mt = 0; mt < 4; ++mt)
        #pragma unroll
        for (int ntp = 0; ntp < 2; ++ntp)
          #pragma unroll
          for (int eo = 0; eo < 2; ++eo)
            acc[mt][ntp][eo] = __builtin_amdgcn_mfma_f32_16x16x32_bf16(
                a[mt], bb[ntp][eo], acc[mt][ntp][eo], 0, 0, 0);
    }
  } else {             // f16 composite path
    #pragma unroll
    for (int ks = 0; ks < 4; ++ks) {
      f16x8 a[4], bb[2][2];
      #pragma unroll
      for (int ntp = 0; ntp < 2; ++ntp)
        #pragma unroll
        for (int eo = 0; eo < 2; ++eo)
          bb[ntp][eo] = *(const f16x8*)(wsrc +
              (size_t)(c0 + ntp * 32 + 2 * lid + eo) * WIDTH + ks * 32 + quad * 8);
      if (f32) {
        #pragma unroll
        for (int mt = 0; mt < 4; ++mt) {
          const float4* xr = (const float4*)((const float*)x +
              (size_t)(node0 + mt * 16 + lid) * WIDTH + ks * 32 + quad * 8);
          a[mt] = cvt8h(xr[0], xr[1]);
        }
      } else {
        #pragma unroll
        for (int mt = 0; mt < 4; ++mt)
          a[mt] = cvtbh(*(const bf16x8*)((const u16*)x +
              (size_t)(node0 + mt * 16 + lid) * WIDTH + ks * 32 + quad * 8));
      }
      #pragma unroll
      for (int mt = 0; mt < 4; ++mt)
        #pragma unroll
        for (int ntp = 0; ntp < 2; ++ntp)
          #pragma unroll
          for (int eo = 0; eo < 2; ++eo)
            acc[mt][ntp][eo] = __builtin_amdgcn_mfma_f32_16x16x32_f16(
                a[mt], bb[ntp][eo], acc[mt][ntp][eo], 0, 0, 0);
    }
  }

  // epilogue: adjacent-pair pack, dword stores (plane-major for mats 0-2)
  #pragma unroll
  for (int mt = 0; mt < 4; ++mt)
    #pragma unroll
    for (int r = 0; r < 4; ++r) {
      const int node = node0 + mt * 16 + quad * 4 + r;
      #pragma unroll
      for (int ntp = 0; ntp < 2; ++ntp) {
        const int p = (c0 >> 1) + ntp * 16 + lid;
        const u32 pk = h2u(__builtin_amdgcn_cvt_pkrtz(
            acc[mt][ntp][0][r], acc[mt][ntp][1][r]));
        if (mat < 3) pk3[(size_t)node * 192 + mat * 64 + p] = pk;
        else         h1d[(size_t)node * 64 + p] = pk;
      }
    }
}

// ---------------------------------------------------------------------------
// k_scan3: full exclusive scan (folds scan2's bsum prefix in per block).
// ---------------------------------------------------------------------------
__global__ void k_scan3(const int* __restrict__ cnt, const int* __restrict__ bsum,
                        int* __restrict__ off, int n){
  const int t = threadIdx.x, b = blockIdx.x;
  __shared__ int sp[256];
  int pv = 0;
  for (int j = t; j < b; j += 256) pv += bsum[j];
  sp[t] = pv; __syncthreads();
  for (int d = 128; d > 0; d >>= 1) { if (t < d) sp[t] += sp[t + d]; __syncthreads(); }
  const int bpref = sp[0];

  const int i0 = b * 1024 + t * 4;
  int c[4];
  #pragma unroll
  for (int j = 0; j < 4; ++j) { int i = i0 + j; c[j] = (i < n) ? cnt[i] : 0; }
  int tsum = c[0] + c[1] + c[2] + c[3];
  __shared__ int sb[256];
  sb[t] = tsum; __syncthreads();
  for (int d = 1; d < 256; d <<= 1) {
    int x = (t >= d) ? sb[t - d] : 0;
    __syncthreads();
    sb[t] += x;
    __syncthreads();
  }
  int run = bpref + sb[t] - tsum;
  #pragma unroll
  for (int j = 0; j < 4; ++j) {
    int i = i0 + j;
    if (i < n) off[i] = run;
    run += c[j];
  }
}

// scatter edges into dst-sorted order; one 8B store per edge; cb at bits 18-19.
// off[dst] becomes END pointer after this.
__global__ void k_scatter(const int* __restrict__ eidx, const int* __restrict__ eattr,
                          int* __restrict__ off, uint2* __restrict__ sedge, int E){
  const int e = blockIdx.x * 256 + threadIdx.x;
  if (e >= E) return;
  const int dst = eidx[E + e];
  const int pos = atomicAdd(&off[dst], 1);
  const u32 a0 = (u32)eattr[e*3+0], a1 = (u32)eattr[e*3+1], a2 = (u32)eattr[e*3+2];
  u32 cb = (a0 != 0) + (a1 != 0) + (a2 != 0);
  cb = cb ? cb : 1u;
  sedge[pos] = make_uint2((u32)eidx[e], a0 | (a1 << 6) | (a2 << 12) | (cb << 18));
}

// ---------------------------------------------------------------------------
// k_agg: one wave per 4 consecutive dst nodes. Lane q owns channels
// {2q,2q+1}; 8-lane clusters = one 16-ch head. gemb + conv weights in LDS.
// Per dst:  DSTEP swizzle conv of h1 row (ug1/uv1), pk_fma_f16, LDS weights.
// Per edge: ONE pk3 address chain -> 3 dword loads @ imm offsets 0/256/512B
//           + 3 ds_read gemb; stats butterfly via ds_swizzle (LDS pipe).
// ---------------------------------------------------------------------------
__global__ __launch_bounds__(256, 6) void k_agg(
    const u32* __restrict__ pk3, const u32* __restrict__ h1d,
    const uint2* __restrict__ sedge, const int* __restrict__ off,
    const u16* __restrict__ pb16, const u32* __restrict__ gembw,
    const float* __restrict__ gsums, u16* __restrict__ aggh, const int N)
{
  __shared__ u32 gl[2112];             // gemb f16[33][128] as u32 pairs
  __shared__ u32 wL[64 * 33];          // per-lane conv weights, padded rows
  for (int j = threadIdx.x; j < 2112; j += 256) gl[j] = gembw[j];
  {
    const u32* gwp = (const u32*)(pb16 + OFF_GW);
    const u32* vwp = (const u32*)(pb16 + OFF_VW);
    for (int j = threadIdx.x; j < 2048; j += 256) {
      const int qq = j >> 5, k = j & 31;
      const u32 v = (k < 16) ? gwp[qq * 16 + k] : vwp[qq * 16 + (k & 15)];
      wL[qq * 33 + k] = v;             // [0..7]=gw0 [8..15]=gw1 [16..23]=vw0 [24..31]=vw1
    }
  }
  __syncthreads();

  const int base = ((blockIdx.x * 256 + threadIdx.x) >> 6) * 4;
  if (base >= N) return;
  const int q = threadIdx.x & 63;
  const int c0 = 2 * q;           // my channels: c0, c0+1
  const u32* wme = wL + q * 33;   // my 32 packed weight words

  const float gs0 = gsums[c0],       gs1 = gsums[c0 + 1];
  const float vs0 = gsums[128 + c0], vs1 = gsums[128 + c0 + 1];

  u32 h1w[4]; int nend[4];
  #pragma unroll
  for (int d = 0; d < 4; ++d) {
    const int dst = min(base + d, N - 1);
    h1w[d]  = h1d[(size_t)dst * 64 + q];
    nend[d] = off[dst];
  }
  int ncur = base ? off[base - 1] : 0;
  const int nlast = nend[3];

  // pipeline: edn = descriptor for edge i+1; payload regs for edge i
  u32 hp = 0, ugp = 0, uvp = 0, g0w = 0, g1w = 0, g2w = 0; float pinv = 1.f;
  uint2 edn = make_uint2(0u, 0u);
  if (ncur < nlast) {
    const uint2 e0 = sedge[ncur];
    edn = sedge[min(ncur + 1, nlast - 1)];
    const u32* pp = pk3 + (size_t)e0.x * 192u + (u32)q;
    hp  = pp[0];
    ugp = pp[64];
    uvp = pp[128];
    const int a0 = e0.y & 63, a1 = (e0.y >> 6) & 63, a2 = (e0.y >> 12) & 63;
    g0w = gl[a0 * 64 + q];
    g1w = gl[a1 * 64 + q];
    g2w = gl[a2 * 64 + q];
    pinv = __builtin_amdgcn_rcpf((float)((e0.y >> 18) & 3));
  }

  #pragma unroll
  for (int d = 0; d < 4; ++d) {
    const f16x2 h1h = u2h(h1w[d]);

    // per-dst grouped conv of h1 row: LDS weights @ immediate offsets
    f16x2 ag0 = u2h(0), ag1 = u2h(0), av0 = u2h(0), av1 = u2h(0);
#define DSTEP(J) {                                                             \
    const f16x2 xj = u2h((u32)__builtin_amdgcn_ds_swizzle(                     \
        (int)h1w[d], 0x18 | ((J) << 5)));                                      \
    ag0 = pkhfma(xj, u2h(wme[(J)]),      ag0);                                 \
    ag1 = pkhfma(xj, u2h(wme[8 + (J)]),  ag1);                                 \
    av0 = pkhfma(xj, u2h(wme[16 + (J)]), av0);                                 \
    av1 = pkhfma(xj, u2h(wme[24 + (J)]), av1); }
    DSTEP(0) DSTEP(1) DSTEP(2) DSTEP(3) DSTEP(4) DSTEP(5) DSTEP(6) DSTEP(7)
#undef DSTEP
    const float ug1d0 = (float)ag0.x + (float)ag0.y;
    const float ug1d1 = (float)ag1.x + (float)ag1.y;
    const float uv1d0 = (float)av0.x + (float)av0.y;
    const float uv1d1 = (float)av1.x + (float)av1.y;

    const int n1 = nend[d];
    float acc0 = 0.f, acc1 = 0.f;

    for (int i = ncur; i < n1; ++i) {
      const u32 hp_c = hp, ug_c = ugp, uv_c = uvp;
      const u32 g0c = g0w, g1c = g1w, g2c = g2w;
      const float inv_c = pinv;
      {                                     // prefetch payload for i+1
        const uint2 en = edn;
        edn = sedge[min(i + 2, nlast - 1)]; // descriptor 2 ahead
        const u32* pp = pk3 + (size_t)en.x * 192u + (u32)q;
        hp  = pp[0];
        ugp = pp[64];
        uvp = pp[128];
        const int a0 = en.y & 63, a1 = (en.y >> 6) & 63, a2 = (en.y >> 12) & 63;
        g0w = gl[a0 * 64 + q];
        g1w = gl[a1 * 64 + q];
        g2w = gl[a2 * 64 + q];
        pinv = __builtin_amdgcn_rcpf((float)((en.y >> 18) & 3));
      }

      // x = h0[src] + h1[dst], packed f16 (raw, un-normalized)
      const f16x2 xh = u2h(hp_c) + h1h;
      const float x0 = (float)xh.x, x1 = (float)xh.y;

      // stats over 16-ch head via ds_swizzle butterfly (LDS pipe)
      float s  = x0 + x1;
      float ss = fmaf(x0, x0, x1 * x1);
      s  += SWZF(s,  0x041F); ss += SWZF(ss, 0x041F);   // xor1
      s  += SWZF(s,  0x081F); ss += SWZF(ss, 0x081F);   // xor2
      s  += SWZF(s,  0x101F); ss += SWZF(ss, 0x101F);   // xor4
      const float mean = s * 0.0625f;
      const float var  = fmaf(ss, 0.0625f, -mean * mean);
      const float rs   = __builtin_amdgcn_rsqf(var + 1e-5f);
      const float mrs  = mean * rs;

      // bag (pre-projected through gate weights), f16 sum then scale
      const f16x2 bsum3 = u2h(g0c) + u2h(g1c) + u2h(g2c);
      const float bg0 = (float)bsum3.x * inv_c;
      const float bg1 = (float)bsum3.y * inv_c;

      // gate = rs*(ug0+ug1) - mrs*gsum + bag ; val = rs*(uv0+uv1) - mrs*vsum
      const f16x2 ugh = u2h(ug_c), uvh = u2h(uv_c);
      const float gate0 = fmaf(rs, (float)ugh.x + ug1d0, fmaf(-mrs, gs0, bg0));
      const float gate1 = fmaf(rs, (float)ugh.y + ug1d1, fmaf(-mrs, gs1, bg1));
      const float val0  = fmaf(rs, (float)uvh.x + uv1d0, -mrs * vs0);
      const float val1  = fmaf(rs, (float)uvh.y + uv1d1, -mrs * vs1);
      acc0 = fmaf(fmaxf(gate0, 0.f), val0, acc0);
      acc1 = fmaf(fmaxf(gate1, 0.f), val1, acc1);
    }

    if (base + d < N)
      *(u32*)(aggh + (size_t)(base + d) * WIDTH + c0) =
          h2u(__builtin_amdgcn_cvt_pkrtz(acc0, acc1));
    ncur = n1;
  }
}

// ---------------------------------------------------------------------------
// k_post: out = (agg @ pw^T + pb) * deg^dp via f16 MFMA (agg & pw are f16).
// ---------------------------------------------------------------------------
__global__ __launch_bounds__(256, 2) void k_post(
    const u16* __restrict__ aggh, const u16* __restrict__ pb16,
    void* __restrict__ out, const void* __restrict__ degsrc)
{
  const int t = threadIdx.x;
  const int lane = t & 63, lid = lane & 15, quad = lane >> 4;
  const int w = t >> 6, c0 = (w & 1) * 64, mh = (w >> 1) * 32;
  const int node0 = blockIdx.x * 64;
  const bool f32o = is_fp32(degsrc);

  f32x4 acc[2][4];
  float dpc[4];
  #pragma unroll
  for (int nt = 0; nt < 4; ++nt) {
    const float bias = b2f(pb16[OFF_PB + c0 + nt * 16 + lid]);
    dpc[nt] = b2f(pb16[OFF_DP + c0 + nt * 16 + lid]);
    #pragma unroll
    for (int mt = 0; mt < 2; ++mt)
      #pragma unroll
      for (int r = 0; r < 4; ++r) acc[mt][nt][r] = bias;
  }

  #pragma unroll
  for (int ks = 0; ks < 4; ++ks) {
    f16x8 a[2], b[4];
    #pragma unroll
    for (int nt = 0; nt < 4; ++nt)
      b[nt] = *(const f16x8*)(pb16 + OFF_PW + (size_t)(c0 + nt * 16 + lid) * WIDTH + ks * 32 + quad * 8);
    #pragma unroll
    for (int mt = 0; mt < 2; ++mt)
      a[mt] = *(const f16x8*)(aggh +
          (size_t)(node0 + mh + mt * 16 + lid) * WIDTH + ks * 32 + quad * 8);
    #pragma unroll
    for (int mt = 0; mt < 2; ++mt)
      #pragma unroll
      for (int nt = 0; nt < 4; ++nt)
        acc[mt][nt] = __builtin_amdgcn_mfma_f32_16x16x32_f16(a[mt], b[nt], acc[mt][nt], 0, 0, 0);
  }

  float logd[2][4];
  #pragma unroll
  for (int mt = 0; mt < 2; ++mt)
    #pragma unroll
    for (int r = 0; r < 4; ++r)
      logd[mt][r] = __logf(b2f(pb16[OFF_DEG + node0 + mh + mt * 16 + quad * 4 + r]));

  #pragma unroll
  for (int mt = 0; mt < 2; ++mt)
    #pragma unroll
    for (int nt = 0; nt < 4; ++nt)
      #pragma unroll
      for (int r = 0; r < 4; ++r) {
        const int node = node0 + mh + mt * 16 + quad * 4 + r;
        const float v = acc[mt][nt][r] * __expf(dpc[nt] * logd[mt][r]);
        if (f32o) ((float*)out)[(size_t)node * WIDTH + c0 + nt * 16 + lid] = v;
        else      ((u16*)out)[(size_t)node * WIDTH + c0 + nt * 16 + lid] = f2b(v);
      }
}

extern "C" void kernel_launch(void* const* d_in, const int* in_sizes, int n_in,
                              void* d_out, int out_size, void* d_ws, size_t ws_size,
                              hipStream_t stream)
{
  (void)n_in; (void)out_size; (void)ws_size;
  const void* x     = d_in[0];
  const void* deg   = d_in[1];
  const int*  eidx  = (const int*)d_in[2];
  const int*  eattr = (const int*)d_in[3];

  const int N = in_sizes[1];            // 200000
  const int E = in_sizes[2] / 2;        // 1000000

  u16*   aggh = (u16*)d_ws;
  u32*   pk3  = (u32*)(aggh + (size_t)N * WIDTH);    // N*192 u32, plane-major
  u16*   pb16 = (u16*)(pk3 + (size_t)N * 192);
  u16*   gembh= pb16 + ARENA_PAD;
  float* gsums= (float*)(gembh + 33 * WIDTH);
  int*   cnt  = (int*)(gsums + 256);
  int*   off  = cnt + N;
  int*   bsum = off + N;
  uint2* sedge= (uint2*)(bsum + 1024);
  u32*   h1d  = (u32*)d_out;            // N*64 u32 f16-pairs; overwritten by k_post

  const int nbc = (OFF_WGC + N + 255) / 256;
  const int nbh = (E + 255) / 256;      // 3907

  hipMemsetAsync(cnt, 0, (size_t)N * sizeof(int), stream);

  k_init_hist<<<nbh + nbc + 147, 256, 0, stream>>>(
      d_in[4], d_in[5], d_in[6], d_in[7], d_in[8], d_in[9], d_in[10],
      d_in[11], d_in[12], d_in[13], deg, eidx, cnt, E, pb16, gembh, gsums, N);

  const int npre = N / 64;              // 3125
  const int nblk = (N + 1023) / 1024;   // 196
  k_pre_scan1<<<npre + nblk, 512, 0, stream>>>(
      x, pb16, pk3, h1d, deg, cnt, bsum, N, npre);

  k_scan3  <<<nblk, 256, 0, stream>>>(cnt, bsum, off, N);
  k_scatter<<<nbh, 256, 0, stream>>>(eidx, eattr, off, sedge, E);

  k_agg<<<((size_t)N * 16 + 255) / 256, 256, 0, stream>>>(
      pk3, h1d, sedge, off, pb16, (const u32*)gembh, gsums, aggh, N);

  k_post<<<N / 64, 256, 0, stream>>>(aggh, pb16, d_out, deg);
}